// Round 1
// baseline (137.831 us; speedup 1.0000x reference)
//
#include <hip/hip_runtime.h>
#include <hip/hip_bf16.h>
#include <cstdint>

// Problem constants (from reference): B=1024, S=8, H=16, DK=DV=32, D=512
#define NB 1024
#define NS 8
#define NH 16
#define ND 512
#define NM 8192  // NB*NS rows

typedef __attribute__((ext_vector_type(8))) short short8;
typedef __attribute__((ext_vector_type(8))) __bf16 bf16x8;
typedef __attribute__((ext_vector_type(4))) float f32x4;

__device__ __forceinline__ unsigned short f2bf(float f) {
  uint32_t x = __builtin_bit_cast(uint32_t, f);
  x += 0x7fffu + ((x >> 16) & 1u);   // round-to-nearest-even
  return (unsigned short)(x >> 16);
}

__device__ __forceinline__ f32x4 mfma16(short8 a, short8 b, f32x4 c) {
  return __builtin_amdgcn_mfma_f32_16x16x32_bf16(
      __builtin_bit_cast(bf16x8, a), __builtin_bit_cast(bf16x8, b), c, 0, 0, 0);
}

// C[m][n] = sum_k A[m][k] * W[n][k]  (+ bias[n]), A: NMxND f32, W: NDxND f32 (row-major N x K)
// Tile 128x128, BK=32, 4 waves (2x2), each wave 64x64 (4x4 MFMA fragments).
__global__ __launch_bounds__(256) void gemm_f32bf(const float* __restrict__ A,
                                                  const float* __restrict__ W,
                                                  const float* __restrict__ bias,
                                                  float* __restrict__ C) {
  __shared__ unsigned short As[128 * 32];
  __shared__ unsigned short Bs[128 * 32];
  const int tid = threadIdx.x;
  const int lane = tid & 63;
  const int wid = tid >> 6;
  const int wm = wid >> 1, wn = wid & 1;
  const int l15 = lane & 15, l4 = lane >> 4;
  const int mBase = blockIdx.y * 128, nBase = blockIdx.x * 128;
  f32x4 acc[4][4] = {};

  for (int kt = 0; kt < 16; ++kt) {
    const int kBase = kt * 32;
#pragma unroll
    for (int r = 0; r < 2; ++r) {
      const int flat = r * 2048 + tid * 8;  // element index in 128x32 tile
      const int row = flat >> 5, kk = flat & 31;
      const float4* pa = (const float4*)(A + (size_t)(mBase + row) * ND + kBase + kk);
      const float4* pb = (const float4*)(W + (size_t)(nBase + row) * ND + kBase + kk);
      float4 a0 = pa[0], a1 = pa[1];
      float4 b0 = pb[0], b1 = pb[1];
      short8 av, bv;
      av[0] = (short)f2bf(a0.x); av[1] = (short)f2bf(a0.y);
      av[2] = (short)f2bf(a0.z); av[3] = (short)f2bf(a0.w);
      av[4] = (short)f2bf(a1.x); av[5] = (short)f2bf(a1.y);
      av[6] = (short)f2bf(a1.z); av[7] = (short)f2bf(a1.w);
      bv[0] = (short)f2bf(b0.x); bv[1] = (short)f2bf(b0.y);
      bv[2] = (short)f2bf(b0.z); bv[3] = (short)f2bf(b0.w);
      bv[4] = (short)f2bf(b1.x); bv[5] = (short)f2bf(b1.y);
      bv[6] = (short)f2bf(b1.z); bv[7] = (short)f2bf(b1.w);
      *(short8*)&As[flat] = av;
      *(short8*)&Bs[flat] = bv;
    }
    __syncthreads();
    short8 af[4], bfr[4];
#pragma unroll
    for (int m = 0; m < 4; ++m)
      af[m] = *(const short8*)&As[(wm * 64 + m * 16 + l15) * 32 + l4 * 8];
#pragma unroll
    for (int n = 0; n < 4; ++n)
      bfr[n] = *(const short8*)&Bs[(wn * 64 + n * 16 + l15) * 32 + l4 * 8];
#pragma unroll
    for (int m = 0; m < 4; ++m)
#pragma unroll
      for (int n = 0; n < 4; ++n)
        acc[m][n] = mfma16(af[m], bfr[n], acc[m][n]);
    __syncthreads();
  }

  // C/D layout: col = lane&15, row = (lane>>4)*4 + r   [measured m89/m91]
#pragma unroll
  for (int m = 0; m < 4; ++m) {
#pragma unroll
    for (int n = 0; n < 4; ++n) {
      const int gn = nBase + wn * 64 + n * 16 + l15;
      const float bb = bias ? bias[gn] : 0.f;
#pragma unroll
      for (int r = 0; r < 4; ++r) {
        const int gm = mBase + wm * 64 + m * 16 + l4 * 4 + r;
        C[(size_t)gm * ND + gn] = acc[m][n][r] + bb;
      }
    }
  }
}

// One wave per (b,h). lane -> (i = lane>>3, j = lane&7) score entry.
__global__ __launch_bounds__(256) void attn_kernel(const float* __restrict__ q,
                                                   const float* __restrict__ k,
                                                   const float* __restrict__ v,
                                                   const int* __restrict__ mask,
                                                   const float* __restrict__ hyper,
                                                   float* __restrict__ wout,
                                                   float* __restrict__ ctx) {
  const int tid = threadIdx.x;
  const int wid = tid >> 6, lane = tid & 63;
  const int t = blockIdx.x * 4 + wid;  // b*16 + h
  const int b = t >> 4, h = t & 15;
  const int i = lane >> 3, j = lane & 7;

  const float* qrow = q + (size_t)(b * 8 + i) * ND + h * 32;
  const float* krow = k + (size_t)(b * 8 + j) * ND + h * 32;
  float dot = 0.f;
#pragma unroll
  for (int c = 0; c < 8; ++c) {
    const float4 qv = ((const float4*)qrow)[c];
    const float4 kv = ((const float4*)krow)[c];
    dot += qv.x * kv.x + qv.y * kv.y + qv.z * kv.z + qv.w * kv.w;
  }
  float score = dot * 0.17677669529663687f;  // 1/sqrt(32)
  if (mask[b * 64 + i * 8 + j]) score = -1e9f;  // mask True -> -1e9

  float mx = score;
#pragma unroll
  for (int o = 4; o; o >>= 1) mx = fmaxf(mx, __shfl_xor(mx, o, 8));
  const float e = __expf(score - mx);
  float sm = e;
#pragma unroll
  for (int o = 4; o; o >>= 1) sm += __shfl_xor(sm, o, 8);
  const float w = e / sm;
  wout[(size_t)t * 64 + lane] = w;  // ((b*16+h)*8+i)*8+j

  // context: lane covers (i = lane>>3, d0 = (lane&7)*4 .. +4)
  const int d0 = (lane & 7) * 4;
  float c0 = 0, c1 = 0, c2 = 0, c3 = 0;
#pragma unroll
  for (int jj = 0; jj < 8; ++jj) {
    const float wj = __shfl(w, jj, 8);  // w[i][jj] from lane (i*8+jj)
    const float4 vv = *(const float4*)(v + (size_t)(b * 8 + jj) * ND + h * 32 + d0);
    c0 += wj * vv.x; c1 += wj * vv.y; c2 += wj * vv.z; c3 += wj * vv.w;
  }
  const float4 hv = *(const float4*)(hyper + (size_t)b * 4096 + h * 256 + i * 32 + d0);
  float4 co;
  co.x = c0 * hv.x; co.y = c1 * hv.y; co.z = c2 * hv.z; co.w = c3 * hv.w;
  *(float4*)(ctx + (size_t)(b * 8 + i) * ND + h * 32 + d0) = co;
}

// In-place: io = LN(io + bo + Q) * g + b.  One wave per row of 512.
__global__ __launch_bounds__(256) void ln_kernel(float* __restrict__ io,
                                                 const float* __restrict__ Qin,
                                                 const float* __restrict__ bo,
                                                 const float* __restrict__ g,
                                                 const float* __restrict__ be) {
  const int tid = threadIdx.x, wid = tid >> 6, lane = tid & 63;
  const size_t row = (size_t)blockIdx.x * 4 + wid;
  float* prow = io + row * ND + lane * 8;
  const float* qrow = Qin + row * ND + lane * 8;
  float4 x0 = ((float4*)prow)[0], x1 = ((float4*)prow)[1];
  const float4 q0 = ((const float4*)qrow)[0], q1 = ((const float4*)qrow)[1];
  const float4 b0 = ((const float4*)(bo + lane * 8))[0];
  const float4 b1 = ((const float4*)(bo + lane * 8))[1];
  x0.x += q0.x + b0.x; x0.y += q0.y + b0.y; x0.z += q0.z + b0.z; x0.w += q0.w + b0.w;
  x1.x += q1.x + b1.x; x1.y += q1.y + b1.y; x1.z += q1.z + b1.z; x1.w += q1.w + b1.w;
  float s = x0.x + x0.y + x0.z + x0.w + x1.x + x1.y + x1.z + x1.w;
  float sq = x0.x * x0.x + x0.y * x0.y + x0.z * x0.z + x0.w * x0.w +
             x1.x * x1.x + x1.y * x1.y + x1.z * x1.z + x1.w * x1.w;
#pragma unroll
  for (int o = 32; o; o >>= 1) {
    s += __shfl_xor(s, o, 64);
    sq += __shfl_xor(sq, o, 64);
  }
  const float mu = s * (1.f / 512.f);
  const float inv = rsqrtf(sq * (1.f / 512.f) - mu * mu + 1e-5f);
  const float4 g0 = ((const float4*)(g + lane * 8))[0];
  const float4 g1 = ((const float4*)(g + lane * 8))[1];
  const float4 e0 = ((const float4*)(be + lane * 8))[0];
  const float4 e1 = ((const float4*)(be + lane * 8))[1];
  float4 o0, o1;
  o0.x = (x0.x - mu) * inv * g0.x + e0.x; o0.y = (x0.y - mu) * inv * g0.y + e0.y;
  o0.z = (x0.z - mu) * inv * g0.z + e0.z; o0.w = (x0.w - mu) * inv * g0.w + e0.w;
  o1.x = (x1.x - mu) * inv * g1.x + e1.x; o1.y = (x1.y - mu) * inv * g1.y + e1.y;
  o1.z = (x1.z - mu) * inv * g1.z + e1.z; o1.w = (x1.w - mu) * inv * g1.w + e1.w;
  ((float4*)prow)[0] = o0;
  ((float4*)prow)[1] = o1;
}

extern "C" void kernel_launch(void* const* d_in, const int* in_sizes, int n_in,
                              void* d_out, int out_size, void* d_ws, size_t ws_size,
                              hipStream_t stream) {
  const float* Q = (const float*)d_in[0];
  const float* K = (const float*)d_in[1];
  const float* V = (const float*)d_in[2];
  const int* msk = (const int*)d_in[3];
  const float* hyper = (const float*)d_in[4];
  const float* Wq = (const float*)d_in[5];
  const float* bq = (const float*)d_in[6];
  const float* Wk = (const float*)d_in[7];
  const float* bk = (const float*)d_in[8];
  const float* Wv = (const float*)d_in[9];
  const float* bv = (const float*)d_in[10];
  const float* Wo = (const float*)d_in[11];
  const float* bo = (const float*)d_in[12];
  const float* lg = (const float*)d_in[13];
  const float* lb = (const float*)d_in[14];

  float* out = (float*)d_out;               // [8192, 512] fp32
  float* wout = out + (size_t)NM * ND;      // [1024,16,8,8] fp32 weights

  float* q = (float*)d_ws;                  // 4 x 16.8 MB fp32 scratch
  float* k = q + (size_t)NM * ND;
  float* v = k + (size_t)NM * ND;
  float* ctx = v + (size_t)NM * ND;

  const dim3 gg(4, 64);  // N/128, M/128
  gemm_f32bf<<<gg, 256, 0, stream>>>(Q, Wq, bq, q);
  gemm_f32bf<<<gg, 256, 0, stream>>>(K, Wk, bk, k);
  gemm_f32bf<<<gg, 256, 0, stream>>>(V, Wv, bv, v);
  attn_kernel<<<4096, 256, 0, stream>>>(q, k, v, msk, hyper, wout, ctx);
  gemm_f32bf<<<gg, 256, 0, stream>>>(ctx, Wo, nullptr, out);
  ln_kernel<<<2048, 256, 0, stream>>>(out, Q, bo, lg, lb);
}

// Round 2
// 80.142 us; speedup vs baseline: 1.7198x; 1.7198x over previous
//
#include <hip/hip_runtime.h>
#include <hip/hip_bf16.h>
#include <cstdint>

// Problem constants: B=1024, S=8, H=16, DK=DV=32, D=512
#define NB 1024
#define ND 512
#define NM 8192  // B*S rows

typedef __attribute__((ext_vector_type(8))) short short8;
typedef __attribute__((ext_vector_type(8))) __bf16 bf16x8;
typedef __attribute__((ext_vector_type(4))) float f32x4;
typedef __attribute__((ext_vector_type(4))) unsigned short ushort4v;

__device__ __forceinline__ unsigned short f2bf(float f) {
  uint32_t x = __builtin_bit_cast(uint32_t, f);
  x += 0x7fffu + ((x >> 16) & 1u);  // RNE
  return (unsigned short)(x >> 16);
}
__device__ __forceinline__ float bf2f(unsigned short u) {
  return __builtin_bit_cast(float, (uint32_t)u << 16);
}
__device__ __forceinline__ f32x4 mfma16(short8 a, short8 b, f32x4 c) {
  return __builtin_amdgcn_mfma_f32_16x16x32_bf16(
      __builtin_bit_cast(bf16x8, a), __builtin_bit_cast(bf16x8, b), c, 0, 0, 0);
}

// ---- fp32 -> bf16 pre-convert: Q,K,V (3 x 4194304) + Wq,Wk,Wv,Wo (4 x 262144)
__global__ __launch_bounds__(256) void convert_kernel(
    const float* __restrict__ Q, const float* __restrict__ K, const float* __restrict__ V,
    const float* __restrict__ Wq, const float* __restrict__ Wk, const float* __restrict__ Wv,
    const float* __restrict__ Wo,
    unsigned short* __restrict__ Qb, unsigned short* __restrict__ Kb,
    unsigned short* __restrict__ Vb, unsigned short* __restrict__ Wqb,
    unsigned short* __restrict__ Wkb, unsigned short* __restrict__ Wvb,
    unsigned short* __restrict__ Wob) {
  const int idx = blockIdx.x * 256 + threadIdx.x;  // one 8-elem chunk each
  const float* src;
  unsigned short* dst;
  int off;
  if (idx < 3 * 524288) {
    const int sel = idx >> 19, o = idx & 524287;
    src = sel == 0 ? Q : sel == 1 ? K : V;
    dst = sel == 0 ? Qb : sel == 1 ? Kb : Vb;
    off = o * 8;
  } else {
    const int w = idx - 3 * 524288;
    const int sel = w >> 15, o = w & 32767;
    src = sel == 0 ? Wq : sel == 1 ? Wk : sel == 2 ? Wv : Wo;
    dst = sel == 0 ? Wqb : sel == 1 ? Wkb : sel == 2 ? Wvb : Wob;
    off = o * 8;
  }
  const float4 a = ((const float4*)(src + off))[0];
  const float4 b = ((const float4*)(src + off))[1];
  short8 r;
  r[0] = (short)f2bf(a.x); r[1] = (short)f2bf(a.y);
  r[2] = (short)f2bf(a.z); r[3] = (short)f2bf(a.w);
  r[4] = (short)f2bf(b.x); r[5] = (short)f2bf(b.y);
  r[6] = (short)f2bf(b.z); r[7] = (short)f2bf(b.w);
  *(short8*)(dst + off) = r;
}

// ---- GEMM tile core: C[m][n] = A[m][:] . W[n][:] (+bias), all-bf16 inputs.
// 128x128 tile, BK=64, 512 threads (8 waves 2x4, wave tile 64x32, acc 4x2).
// LDS XOR-swizzle: byte ^= (row&7)<<4  (write and read sides) -> conflict-free b128.
template <bool OUT_BF16>
__device__ __forceinline__ void gemm_tile(const unsigned short* __restrict__ A,
                                          const unsigned short* __restrict__ W,
                                          const float* __restrict__ bias,
                                          void* __restrict__ C, int mBase, int nBase) {
  __shared__ unsigned short As[128 * 64];
  __shared__ unsigned short Bs[128 * 64];
  const int tid = threadIdx.x;
  const int lane = tid & 63, wid = tid >> 6;
  const int wm = wid >> 2, wn = wid & 3;
  const int l15 = lane & 15, l4 = lane >> 4;
  f32x4 acc[4][2] = {};

  for (int kt = 0; kt < 8; ++kt) {
    const int kBase = kt * 64;
#pragma unroll
    for (int i = 0; i < 2; ++i) {
      const int Lb = i * 8192 + tid * 16;  // logical byte offset in 128x64 tile
      const int r = Lb >> 7;
      const int ce = (Lb & 127) >> 1;  // element col
      const int P = Lb ^ ((r & 7) << 4);
      const short8 av = *(const short8*)(A + (size_t)(mBase + r) * ND + kBase + ce);
      const short8 wv = *(const short8*)(W + (size_t)(nBase + r) * ND + kBase + ce);
      *(short8*)((char*)As + P) = av;
      *(short8*)((char*)Bs + P) = wv;
    }
    __syncthreads();
#pragma unroll
    for (int kk = 0; kk < 2; ++kk) {
      short8 af[4], bf4[2];
#pragma unroll
      for (int m = 0; m < 4; ++m) {
        const int r = wm * 64 + m * 16 + l15;
        const int Lb = r * 128 + kk * 64 + l4 * 16;
        af[m] = *(const short8*)((char*)As + (Lb ^ ((r & 7) << 4)));
      }
#pragma unroll
      for (int n = 0; n < 2; ++n) {
        const int r = wn * 32 + n * 16 + l15;
        const int Lb = r * 128 + kk * 64 + l4 * 16;
        bf4[n] = *(const short8*)((char*)Bs + (Lb ^ ((r & 7) << 4)));
      }
#pragma unroll
      for (int m = 0; m < 4; ++m)
#pragma unroll
        for (int n = 0; n < 2; ++n)
          acc[m][n] = mfma16(af[m], bf4[n], acc[m][n]);
    }
    __syncthreads();
  }

  // C/D layout: col = lane&15, row = (lane>>4)*4 + r  [verified round 1]
#pragma unroll
  for (int m = 0; m < 4; ++m)
#pragma unroll
    for (int n = 0; n < 2; ++n) {
      const int gn = nBase + wn * 32 + n * 16 + l15;
      const float bb = bias ? bias[gn] : 0.f;
#pragma unroll
      for (int r4 = 0; r4 < 4; ++r4) {
        const int gm = mBase + wm * 64 + m * 16 + l4 * 4 + r4;
        const float val = acc[m][n][r4] + bb;
        if (OUT_BF16)
          ((unsigned short*)C)[(size_t)gm * ND + gn] = f2bf(val);
        else
          ((float*)C)[(size_t)gm * ND + gn] = val;
      }
    }
}

// Fused QKV projection: grid (12, 64); n-block selects segment (Q/K/V).
__global__ __launch_bounds__(512) void gemm_qkv(
    const unsigned short* __restrict__ Qb, const unsigned short* __restrict__ Kb,
    const unsigned short* __restrict__ Vb, const unsigned short* __restrict__ Wqb,
    const unsigned short* __restrict__ Wkb, const unsigned short* __restrict__ Wvb,
    const float* __restrict__ bq, const float* __restrict__ bk,
    const float* __restrict__ bv, unsigned short* __restrict__ qo,
    unsigned short* __restrict__ ko, unsigned short* __restrict__ vo) {
  const int nb = blockIdx.x;
  const int seg = nb >> 2, nloc = nb & 3;
  const unsigned short* A = seg == 0 ? Qb : seg == 1 ? Kb : Vb;
  const unsigned short* W = seg == 0 ? Wqb : seg == 1 ? Wkb : Wvb;
  const float* bias = seg == 0 ? bq : seg == 1 ? bk : bv;
  unsigned short* C = seg == 0 ? qo : seg == 1 ? ko : vo;
  gemm_tile<true>(A, W, bias, C, blockIdx.y * 128, nloc * 128);
}

__global__ __launch_bounds__(512) void gemm_wo(const unsigned short* __restrict__ ctx,
                                               const unsigned short* __restrict__ Wob,
                                               float* __restrict__ out) {
  gemm_tile<false>(ctx, Wob, nullptr, out, blockIdx.y * 128, blockIdx.x * 128);
}

// ---- attention: one wave per (b,h); lane -> (i=lane>>3, j=lane&7)
__global__ __launch_bounds__(256) void attn_kernel(
    const unsigned short* __restrict__ q, const unsigned short* __restrict__ k,
    const unsigned short* __restrict__ v, const int* __restrict__ mask,
    const float* __restrict__ hyper, float* __restrict__ wout,
    unsigned short* __restrict__ ctx) {
  const int tid = threadIdx.x;
  const int wid = tid >> 6, lane = tid & 63;
  const int t = blockIdx.x * 4 + wid;  // b*16 + h
  const int b = t >> 4, h = t & 15;
  const int i = lane >> 3, j = lane & 7;

  const unsigned short* qrow = q + (size_t)(b * 8 + i) * ND + h * 32;
  const unsigned short* krow = k + (size_t)(b * 8 + j) * ND + h * 32;
  float dot = 0.f;
#pragma unroll
  for (int c = 0; c < 4; ++c) {
    const short8 qv = ((const short8*)qrow)[c];
    const short8 kv = ((const short8*)krow)[c];
#pragma unroll
    for (int e = 0; e < 8; ++e)
      dot += bf2f((unsigned short)qv[e]) * bf2f((unsigned short)kv[e]);
  }
  float score = dot * 0.17677669529663687f;  // 1/sqrt(32)
  if (mask[b * 64 + i * 8 + j]) score = -1e9f;

  float mx = score;
#pragma unroll
  for (int o = 4; o; o >>= 1) mx = fmaxf(mx, __shfl_xor(mx, o, 8));
  const float e = __expf(score - mx);
  float sm = e;
#pragma unroll
  for (int o = 4; o; o >>= 1) sm += __shfl_xor(sm, o, 8);
  const float w = e / sm;
  wout[(size_t)t * 64 + lane] = w;

  // context: lane covers (i = lane>>3, d0 = (lane&7)*4 .. +4)
  const int d0 = (lane & 7) * 4;
  float c0 = 0, c1 = 0, c2 = 0, c3 = 0;
#pragma unroll
  for (int jj = 0; jj < 8; ++jj) {
    const float wj = __shfl(w, jj, 8);
    const ushort4v vv = *(const ushort4v*)(v + (size_t)(b * 8 + jj) * ND + h * 32 + d0);
    c0 += wj * bf2f(vv[0]); c1 += wj * bf2f(vv[1]);
    c2 += wj * bf2f(vv[2]); c3 += wj * bf2f(vv[3]);
  }
  const float4 hv = *(const float4*)(hyper + (size_t)b * 4096 + h * 256 + i * 32 + d0);
  ushort4v co;
  co[0] = f2bf(c0 * hv.x); co[1] = f2bf(c1 * hv.y);
  co[2] = f2bf(c2 * hv.z); co[3] = f2bf(c3 * hv.w);
  *(ushort4v*)(ctx + (size_t)(b * 8 + i) * ND + h * 32 + d0) = co;
}

// ---- in-place: io = LN(io + bo + Q) * g + b. One wave per 512-row.
__global__ __launch_bounds__(256) void ln_kernel(float* __restrict__ io,
                                                 const float* __restrict__ Qin,
                                                 const float* __restrict__ bo,
                                                 const float* __restrict__ g,
                                                 const float* __restrict__ be) {
  const int tid = threadIdx.x, wid = tid >> 6, lane = tid & 63;
  const size_t row = (size_t)blockIdx.x * 4 + wid;
  float* prow = io + row * ND + lane * 8;
  const float* qrow = Qin + row * ND + lane * 8;
  float4 x0 = ((float4*)prow)[0], x1 = ((float4*)prow)[1];
  const float4 q0 = ((const float4*)qrow)[0], q1 = ((const float4*)qrow)[1];
  const float4 b0 = ((const float4*)(bo + lane * 8))[0];
  const float4 b1 = ((const float4*)(bo + lane * 8))[1];
  x0.x += q0.x + b0.x; x0.y += q0.y + b0.y; x0.z += q0.z + b0.z; x0.w += q0.w + b0.w;
  x1.x += q1.x + b1.x; x1.y += q1.y + b1.y; x1.z += q1.z + b1.z; x1.w += q1.w + b1.w;
  float s = x0.x + x0.y + x0.z + x0.w + x1.x + x1.y + x1.z + x1.w;
  float sq = x0.x * x0.x + x0.y * x0.y + x0.z * x0.z + x0.w * x0.w +
             x1.x * x1.x + x1.y * x1.y + x1.z * x1.z + x1.w * x1.w;
#pragma unroll
  for (int o = 32; o; o >>= 1) {
    s += __shfl_xor(s, o, 64);
    sq += __shfl_xor(sq, o, 64);
  }
  const float mu = s * (1.f / 512.f);
  const float inv = rsqrtf(sq * (1.f / 512.f) - mu * mu + 1e-5f);
  const float4 g0 = ((const float4*)(g + lane * 8))[0];
  const float4 g1 = ((const float4*)(g + lane * 8))[1];
  const float4 e0 = ((const float4*)(be + lane * 8))[0];
  const float4 e1 = ((const float4*)(be + lane * 8))[1];
  float4 o0, o1;
  o0.x = (x0.x - mu) * inv * g0.x + e0.x; o0.y = (x0.y - mu) * inv * g0.y + e0.y;
  o0.z = (x0.z - mu) * inv * g0.z + e0.z; o0.w = (x0.w - mu) * inv * g0.w + e0.w;
  o1.x = (x1.x - mu) * inv * g1.x + e1.x; o1.y = (x1.y - mu) * inv * g1.y + e1.y;
  o1.z = (x1.z - mu) * inv * g1.z + e1.z; o1.w = (x1.w - mu) * inv * g1.w + e1.w;
  ((float4*)prow)[0] = o0;
  ((float4*)prow)[1] = o1;
}

extern "C" void kernel_launch(void* const* d_in, const int* in_sizes, int n_in,
                              void* d_out, int out_size, void* d_ws, size_t ws_size,
                              hipStream_t stream) {
  const float* Q = (const float*)d_in[0];
  const float* K = (const float*)d_in[1];
  const float* V = (const float*)d_in[2];
  const int* msk = (const int*)d_in[3];
  const float* hyper = (const float*)d_in[4];
  const float* Wq = (const float*)d_in[5];
  const float* bq = (const float*)d_in[6];
  const float* Wk = (const float*)d_in[7];
  const float* bk = (const float*)d_in[8];
  const float* Wv = (const float*)d_in[9];
  const float* bv = (const float*)d_in[10];
  const float* Wo = (const float*)d_in[11];
  const float* bo = (const float*)d_in[12];
  const float* lg = (const float*)d_in[13];
  const float* lb = (const float*)d_in[14];

  float* out = (float*)d_out;           // [8192,512] fp32
  float* wout = out + (size_t)NM * ND;  // [1024,16,8,8] fp32

  // ws layout: 7 x 8MB bf16 matrices + 4 x 0.5MB bf16 weights (~59MB of ~256MB)
  const size_t MAT = (size_t)NM * ND;  // elements
  unsigned short* Qb = (unsigned short*)d_ws;
  unsigned short* Kb = Qb + MAT;
  unsigned short* Vb = Kb + MAT;
  unsigned short* qb = Vb + MAT;
  unsigned short* kb = qb + MAT;
  unsigned short* vb = kb + MAT;
  unsigned short* ctxb = vb + MAT;
  unsigned short* Wqb = ctxb + MAT;
  unsigned short* Wkb = Wqb + (size_t)ND * ND;
  unsigned short* Wvb = Wkb + (size_t)ND * ND;
  unsigned short* Wob = Wvb + (size_t)ND * ND;

  convert_kernel<<<6656, 256, 0, stream>>>(Q, K, V, Wq, Wk, Wv, Wo,
                                           Qb, Kb, Vb, Wqb, Wkb, Wvb, Wob);
  gemm_qkv<<<dim3(12, 64), 512, 0, stream>>>(Qb, Kb, Vb, Wqb, Wkb, Wvb,
                                             bq, bk, bv, qb, kb, vb);
  attn_kernel<<<4096, 256, 0, stream>>>(qb, kb, vb, msk, hyper, wout, ctxb);
  gemm_wo<<<dim3(4, 64), 512, 0, stream>>>(ctxb, Wob, out);
  ln_kernel<<<2048, 256, 0, stream>>>(out, Q, bo, lg, lb);
}